// Round 1
// baseline (218.417 us; speedup 1.0000x reference)
//
#include <hip/hip_runtime.h>

#define NN 2048
#define DD 512
#define MM 8

__host__ __device__ constexpr int tri_idx(int m, int mm) {
    // upper-triangle (m <= mm) packed index, 8x8 -> 36
    return m * 8 - m * (m + 1) / 2 + mm;
}

// ---------------------------------------------------------------------------
// Kernel 1: Y = X * X^T.  X is [NN][DD] row-major fp32.
// 64x64 output tile per block, BK=16, 256 threads, 4x4 accum per thread.
// ---------------------------------------------------------------------------
__global__ __launch_bounds__(256) void gemm_xxt(const float* __restrict__ X,
                                                float* __restrict__ Y) {
    __shared__ float As[16][68];   // [k][row], +4 pad keeps float4 alignment, spreads banks
    __shared__ float Bs[16][68];

    const int t = threadIdx.x;
    const int tx = t & 15;         // 0..15 -> output col group
    const int ty = t >> 4;         // 0..15 -> output row group
    const int rowBase = blockIdx.y * 64;
    const int colBase = blockIdx.x * 64;

    // staging mapping: each thread loads one float4 of each tile
    const int lrow = t >> 2;             // 0..63
    const int lk = (t & 3) << 2;         // 0,4,8,12

    float acc[4][4] = {{0.f}};

    for (int k0 = 0; k0 < DD; k0 += 16) {
        float4 av = *reinterpret_cast<const float4*>(&X[(rowBase + lrow) * DD + k0 + lk]);
        float4 bv = *reinterpret_cast<const float4*>(&X[(colBase + lrow) * DD + k0 + lk]);
        __syncthreads();   // previous iteration's reads done before overwrite
        As[lk + 0][lrow] = av.x;
        As[lk + 1][lrow] = av.y;
        As[lk + 2][lrow] = av.z;
        As[lk + 3][lrow] = av.w;
        Bs[lk + 0][lrow] = bv.x;
        Bs[lk + 1][lrow] = bv.y;
        Bs[lk + 2][lrow] = bv.z;
        Bs[lk + 3][lrow] = bv.w;
        __syncthreads();
        #pragma unroll
        for (int kk = 0; kk < 16; ++kk) {
            float4 a4 = *reinterpret_cast<const float4*>(&As[kk][ty << 2]);
            float4 b4 = *reinterpret_cast<const float4*>(&Bs[kk][tx << 2]);
            float ar[4] = {a4.x, a4.y, a4.z, a4.w};
            float br[4] = {b4.x, b4.y, b4.z, b4.w};
            #pragma unroll
            for (int i = 0; i < 4; ++i)
                #pragma unroll
                for (int j = 0; j < 4; ++j)
                    acc[i][j] += ar[i] * br[j];
        }
    }

    #pragma unroll
    for (int i = 0; i < 4; ++i) {
        float4 v = make_float4(acc[i][0], acc[i][1], acc[i][2], acc[i][3]);
        *reinterpret_cast<float4*>(
            &Y[(rowBase + (ty << 2) + i) * NN + colBase + (tx << 2)]) = v;
    }
}

// ---------------------------------------------------------------------------
// Kernel 2: G0 (packed upper triangle, 36) and s0 (8) in one 144MB pass.
// out[0..35] = tri(G0), out[36..43] = s0. Must be pre-zeroed.
// ---------------------------------------------------------------------------
__global__ __launch_bounds__(256) void gram_kernel(const float* __restrict__ A,
                                                   const float* __restrict__ Y,
                                                   float* __restrict__ out) {
    const int P4 = (NN * NN) / 4;
    float vals[44];
    #pragma unroll
    for (int i = 0; i < 44; ++i) vals[i] = 0.f;

    const float4* Y4 = reinterpret_cast<const float4*>(Y);
    const float4* A4 = reinterpret_cast<const float4*>(A);
    const int tid = blockIdx.x * blockDim.x + threadIdx.x;
    const int stride = gridDim.x * blockDim.x;

    for (int p = tid; p < P4; p += stride) {
        float4 y = Y4[p];
        float4 a[MM];
        #pragma unroll
        for (int m = 0; m < MM; ++m) a[m] = A4[m * P4 + p];
        #pragma unroll
        for (int m = 0; m < MM; ++m) {
            vals[36 + m] += a[m].x * y.x + a[m].y * y.y + a[m].z * y.z + a[m].w * y.w;
            #pragma unroll
            for (int mm = m; mm < MM; ++mm) {
                vals[tri_idx(m, mm)] += a[m].x * a[mm].x + a[m].y * a[mm].y +
                                        a[m].z * a[mm].z + a[m].w * a[mm].w;
            }
        }
    }

    // 64-lane wave reduction on each accumulator
    #pragma unroll
    for (int i = 0; i < 44; ++i) {
        float v = vals[i];
        #pragma unroll
        for (int off = 32; off > 0; off >>= 1) v += __shfl_down(v, off);
        vals[i] = v;
    }

    __shared__ float wsum[4][44];
    const int lane = threadIdx.x & 63;
    const int wv = threadIdx.x >> 6;
    if (lane == 0) {
        #pragma unroll
        for (int i = 0; i < 44; ++i) wsum[wv][i] = vals[i];
    }
    __syncthreads();
    if (threadIdx.x < 44) {
        float s = wsum[0][threadIdx.x] + wsum[1][threadIdx.x] +
                  wsum[2][threadIdx.x] + wsum[3][threadIdx.x];
        atomicAdd(&out[threadIdx.x], s);
    }
}

// ---------------------------------------------------------------------------
// Kernel 3: K deflation iterations in 9-dim coefficient space (fp64, 1 thread).
// acc[0..35]=tri(G0), acc[36..43]=s0.  Writes w[8] (Y = Y0 + sum w_m A0_m).
// ---------------------------------------------------------------------------
__global__ void iterate_kernel(const float* __restrict__ acc,
                               const int* __restrict__ Kp,
                               float* __restrict__ w_out) {
    if (threadIdx.x != 0 || blockIdx.x != 0) return;

    double G[MM][MM], s0[MM], T[MM][MM], w[MM];
    int idx = 0;
    for (int m = 0; m < MM; ++m)
        for (int mm = m; mm < MM; ++mm) {
            double v = (double)acc[idx++];
            G[m][mm] = v;
            G[mm][m] = v;
        }
    for (int m = 0; m < MM; ++m) s0[m] = (double)acc[36 + m];
    for (int m = 0; m < MM; ++m) {
        w[m] = 0.0;
        for (int k = 0; k < MM; ++k) T[m][k] = (m == k) ? 1.0 : 0.0;
    }

    const int K = *Kp;
    for (int it = 0; it < K; ++it) {
        double sy[MM];                       // <A0_k, Y> = s0_k + (G w)_k
        for (int k = 0; k < MM; ++k) {
            double acc_ = s0[k];
            for (int j = 0; j < MM; ++j) acc_ += G[k][j] * w[j];
            sy[k] = acc_;
        }
        double s[MM];                        // s_m = <A_m, Y>
        for (int m = 0; m < MM; ++m) {
            double acc_ = 0.0;
            for (int k = 0; k < MM; ++k) acc_ += T[m][k] * sy[k];
            s[m] = acc_;
        }
        double c[MM];                        // C = sum_k c_k A0_k,  c = T^T s
        for (int k = 0; k < MM; ++k) {
            double acc_ = 0.0;
            for (int m = 0; m < MM; ++m) acc_ += T[m][k] * s[m];
            c[k] = acc_;
        }
        double Gc[MM];
        for (int k = 0; k < MM; ++k) {
            double acc_ = 0.0;
            for (int j = 0; j < MM; ++j) acc_ += G[k][j] * c[j];
            Gc[k] = acc_;
        }
        double den = 0.0, num = 0.0;
        for (int k = 0; k < MM; ++k) den += c[k] * Gc[k];
        for (int m = 0; m < MM; ++m) num += s[m] * s[m];
        double alpha = num / den;
        for (int k = 0; k < MM; ++k) w[k] -= alpha * c[k];
        for (int m = 0; m < MM; ++m) {
            double beta = 0.0;
            for (int k = 0; k < MM; ++k) beta += T[m][k] * Gc[k];
            beta /= den;
            for (int k = 0; k < MM; ++k) T[m][k] -= beta * c[k];
        }
    }
    for (int k = 0; k < MM; ++k) w_out[k] = (float)w[k];
}

// ---------------------------------------------------------------------------
// Kernel 4: Y += sum_m w_m * A0_m   (in place on d_out)
// ---------------------------------------------------------------------------
__global__ __launch_bounds__(256) void reconstruct(const float* __restrict__ A,
                                                   const float* __restrict__ w,
                                                   float* __restrict__ Y) {
    __shared__ float wsh[MM];
    if (threadIdx.x < MM) wsh[threadIdx.x] = w[threadIdx.x];
    __syncthreads();
    float wl[MM];
    #pragma unroll
    for (int m = 0; m < MM; ++m) wl[m] = wsh[m];

    const int P4 = (NN * NN) / 4;
    float4* Y4 = reinterpret_cast<float4*>(Y);
    const float4* A4 = reinterpret_cast<const float4*>(A);
    const int tid = blockIdx.x * blockDim.x + threadIdx.x;
    const int stride = gridDim.x * blockDim.x;

    for (int p = tid; p < P4; p += stride) {
        float4 y = Y4[p];
        #pragma unroll
        for (int m = 0; m < MM; ++m) {
            float4 a = A4[m * P4 + p];
            y.x += wl[m] * a.x;
            y.y += wl[m] * a.y;
            y.z += wl[m] * a.z;
            y.w += wl[m] * a.w;
        }
        Y4[p] = y;
    }
}

extern "C" void kernel_launch(void* const* d_in, const int* in_sizes, int n_in,
                              void* d_out, int out_size, void* d_ws, size_t ws_size,
                              hipStream_t stream) {
    const float* X = (const float*)d_in[0];
    const float* A = (const float*)d_in[1];
    const int* Kp = (const int*)d_in[2];
    float* Y = (float*)d_out;

    float* acc = (float*)d_ws;       // [0..43]  G0 triangle + s0
    float* w = acc + 48;             // [48..55] w coefficients

    hipMemsetAsync(d_ws, 0, 44 * sizeof(float), stream);

    gemm_xxt<<<dim3(32, 32), 256, 0, stream>>>(X, Y);
    gram_kernel<<<256, 256, 0, stream>>>(A, Y, acc);
    iterate_kernel<<<1, 64, 0, stream>>>(acc, Kp, w);
    reconstruct<<<2048, 256, 0, stream>>>(A, w, Y);
}

// Round 2
// 143.656 us; speedup vs baseline: 1.5204x; 1.5204x over previous
//
#include <hip/hip_runtime.h>

#define NN 2048
#define DD 512
#define MM 8

__host__ __device__ constexpr int tri_idx(int m, int mm) {
    // upper-triangle (m <= mm) packed index, 8x8 -> 36
    return m * 8 - m * (m + 1) / 2 + mm;
}

// ---------------------------------------------------------------------------
// Kernel 1: Y = X * X^T.  X is [NN][DD] row-major fp32.
// 64x64 output tile per block, BK=16, 256 threads, 4x4 accum per thread.
// ---------------------------------------------------------------------------
__global__ __launch_bounds__(256) void gemm_xxt(const float* __restrict__ X,
                                                float* __restrict__ Y) {
    __shared__ float As[16][68];   // [k][row], +4 pad keeps float4 alignment, spreads banks
    __shared__ float Bs[16][68];

    const int t = threadIdx.x;
    const int tx = t & 15;         // 0..15 -> output col group
    const int ty = t >> 4;         // 0..15 -> output row group
    const int rowBase = blockIdx.y * 64;
    const int colBase = blockIdx.x * 64;

    // staging mapping: each thread loads one float4 of each tile
    const int lrow = t >> 2;             // 0..63
    const int lk = (t & 3) << 2;         // 0,4,8,12

    float acc[4][4] = {{0.f}};

    for (int k0 = 0; k0 < DD; k0 += 16) {
        float4 av = *reinterpret_cast<const float4*>(&X[(rowBase + lrow) * DD + k0 + lk]);
        float4 bv = *reinterpret_cast<const float4*>(&X[(colBase + lrow) * DD + k0 + lk]);
        __syncthreads();   // previous iteration's reads done before overwrite
        As[lk + 0][lrow] = av.x;
        As[lk + 1][lrow] = av.y;
        As[lk + 2][lrow] = av.z;
        As[lk + 3][lrow] = av.w;
        Bs[lk + 0][lrow] = bv.x;
        Bs[lk + 1][lrow] = bv.y;
        Bs[lk + 2][lrow] = bv.z;
        Bs[lk + 3][lrow] = bv.w;
        __syncthreads();
        #pragma unroll
        for (int kk = 0; kk < 16; ++kk) {
            float4 a4 = *reinterpret_cast<const float4*>(&As[kk][ty << 2]);
            float4 b4 = *reinterpret_cast<const float4*>(&Bs[kk][tx << 2]);
            float ar[4] = {a4.x, a4.y, a4.z, a4.w};
            float br[4] = {b4.x, b4.y, b4.z, b4.w};
            #pragma unroll
            for (int i = 0; i < 4; ++i)
                #pragma unroll
                for (int j = 0; j < 4; ++j)
                    acc[i][j] += ar[i] * br[j];
        }
    }

    #pragma unroll
    for (int i = 0; i < 4; ++i) {
        float4 v = make_float4(acc[i][0], acc[i][1], acc[i][2], acc[i][3]);
        *reinterpret_cast<float4*>(
            &Y[(rowBase + (ty << 2) + i) * NN + colBase + (tx << 2)]) = v;
    }
}

// ---------------------------------------------------------------------------
// Kernel 2: G0 (packed upper triangle, 36) and s0 (8) in one 144MB pass.
// out[0..35] = tri(G0), out[36..43] = s0. Must be pre-zeroed.
// ---------------------------------------------------------------------------
__global__ __launch_bounds__(256) void gram_kernel(const float* __restrict__ A,
                                                   const float* __restrict__ Y,
                                                   float* __restrict__ out) {
    const int P4 = (NN * NN) / 4;
    float vals[44];
    #pragma unroll
    for (int i = 0; i < 44; ++i) vals[i] = 0.f;

    const float4* Y4 = reinterpret_cast<const float4*>(Y);
    const float4* A4 = reinterpret_cast<const float4*>(A);
    const int tid = blockIdx.x * blockDim.x + threadIdx.x;
    const int stride = gridDim.x * blockDim.x;

    for (int p = tid; p < P4; p += stride) {
        float4 y = Y4[p];
        float4 a[MM];
        #pragma unroll
        for (int m = 0; m < MM; ++m) a[m] = A4[m * P4 + p];
        #pragma unroll
        for (int m = 0; m < MM; ++m) {
            vals[36 + m] += a[m].x * y.x + a[m].y * y.y + a[m].z * y.z + a[m].w * y.w;
            #pragma unroll
            for (int mm = m; mm < MM; ++mm) {
                vals[tri_idx(m, mm)] += a[m].x * a[mm].x + a[m].y * a[mm].y +
                                        a[m].z * a[mm].z + a[m].w * a[mm].w;
            }
        }
    }

    // 64-lane wave reduction on each accumulator
    #pragma unroll
    for (int i = 0; i < 44; ++i) {
        float v = vals[i];
        #pragma unroll
        for (int off = 32; off > 0; off >>= 1) v += __shfl_down(v, off);
        vals[i] = v;
    }

    __shared__ float wsum[4][44];
    const int lane = threadIdx.x & 63;
    const int wv = threadIdx.x >> 6;
    if (lane == 0) {
        #pragma unroll
        for (int i = 0; i < 44; ++i) wsum[wv][i] = vals[i];
    }
    __syncthreads();
    if (threadIdx.x < 44) {
        float s = wsum[0][threadIdx.x] + wsum[1][threadIdx.x] +
                  wsum[2][threadIdx.x] + wsum[3][threadIdx.x];
        atomicAdd(&out[threadIdx.x], s);
    }
}

// ---------------------------------------------------------------------------
// Kernel 3: K deflation iterations in 9-dim coefficient space (fp64).
// Fully unrolled so G/T/vectors live in VGPRs (not scratch). All 64 lanes
// compute redundantly; lane 0 writes. acc[0..35]=tri(G0), acc[36..43]=s0.
// Writes w[8] (Y = Y0 + sum w_m A0_m).
// ---------------------------------------------------------------------------
__global__ __launch_bounds__(64, 1) void iterate_kernel(const float* __restrict__ acc,
                                                        const int* __restrict__ Kp,
                                                        float* __restrict__ w_out) {
    double G[MM][MM], s0[MM], T[MM][MM], w[MM];
    #pragma unroll
    for (int m = 0; m < MM; ++m) {
        #pragma unroll
        for (int mm = m; mm < MM; ++mm) {
            double v = (double)acc[tri_idx(m, mm)];
            G[m][mm] = v;
            G[mm][m] = v;
        }
    }
    #pragma unroll
    for (int m = 0; m < MM; ++m) s0[m] = (double)acc[36 + m];
    #pragma unroll
    for (int m = 0; m < MM; ++m) {
        w[m] = 0.0;
        #pragma unroll
        for (int k = 0; k < MM; ++k) T[m][k] = (m == k) ? 1.0 : 0.0;
    }

    const int K = *Kp;
    for (int it = 0; it < K; ++it) {
        double sy[MM];                       // <A0_k, Y> = s0_k + (G w)_k
        #pragma unroll
        for (int k = 0; k < MM; ++k) {
            double a = s0[k];
            #pragma unroll
            for (int j = 0; j < MM; ++j) a += G[k][j] * w[j];
            sy[k] = a;
        }
        double s[MM];                        // s_m = <A_m, Y>
        #pragma unroll
        for (int m = 0; m < MM; ++m) {
            double a = 0.0;
            #pragma unroll
            for (int k = 0; k < MM; ++k) a += T[m][k] * sy[k];
            s[m] = a;
        }
        double c[MM];                        // C = sum_k c_k A0_k,  c = T^T s
        #pragma unroll
        for (int k = 0; k < MM; ++k) {
            double a = 0.0;
            #pragma unroll
            for (int m = 0; m < MM; ++m) a += T[m][k] * s[m];
            c[k] = a;
        }
        double Gc[MM];
        #pragma unroll
        for (int k = 0; k < MM; ++k) {
            double a = 0.0;
            #pragma unroll
            for (int j = 0; j < MM; ++j) a += G[k][j] * c[j];
            Gc[k] = a;
        }
        double den = 0.0, num = 0.0;
        #pragma unroll
        for (int k = 0; k < MM; ++k) den += c[k] * Gc[k];
        #pragma unroll
        for (int m = 0; m < MM; ++m) num += s[m] * s[m];
        const double inv_den = 1.0 / den;
        const double alpha = num * inv_den;
        #pragma unroll
        for (int k = 0; k < MM; ++k) w[k] -= alpha * c[k];
        #pragma unroll
        for (int m = 0; m < MM; ++m) {
            double beta = 0.0;
            #pragma unroll
            for (int k = 0; k < MM; ++k) beta += T[m][k] * Gc[k];
            beta *= inv_den;
            #pragma unroll
            for (int k = 0; k < MM; ++k) T[m][k] -= beta * c[k];
        }
    }
    if (threadIdx.x == 0 && blockIdx.x == 0) {
        #pragma unroll
        for (int k = 0; k < MM; ++k) w_out[k] = (float)w[k];
    }
}

// ---------------------------------------------------------------------------
// Kernel 4: Y += sum_m w_m * A0_m   (in place on d_out)
// ---------------------------------------------------------------------------
__global__ __launch_bounds__(256) void reconstruct(const float* __restrict__ A,
                                                   const float* __restrict__ w,
                                                   float* __restrict__ Y) {
    __shared__ float wsh[MM];
    if (threadIdx.x < MM) wsh[threadIdx.x] = w[threadIdx.x];
    __syncthreads();
    float wl[MM];
    #pragma unroll
    for (int m = 0; m < MM; ++m) wl[m] = wsh[m];

    const int P4 = (NN * NN) / 4;
    float4* Y4 = reinterpret_cast<float4*>(Y);
    const float4* A4 = reinterpret_cast<const float4*>(A);
    const int tid = blockIdx.x * blockDim.x + threadIdx.x;
    const int stride = gridDim.x * blockDim.x;

    for (int p = tid; p < P4; p += stride) {
        float4 y = Y4[p];
        #pragma unroll
        for (int m = 0; m < MM; ++m) {
            float4 a = A4[m * P4 + p];
            y.x += wl[m] * a.x;
            y.y += wl[m] * a.y;
            y.z += wl[m] * a.z;
            y.w += wl[m] * a.w;
        }
        Y4[p] = y;
    }
}

extern "C" void kernel_launch(void* const* d_in, const int* in_sizes, int n_in,
                              void* d_out, int out_size, void* d_ws, size_t ws_size,
                              hipStream_t stream) {
    const float* X = (const float*)d_in[0];
    const float* A = (const float*)d_in[1];
    const int* Kp = (const int*)d_in[2];
    float* Y = (float*)d_out;

    float* acc = (float*)d_ws;       // [0..43]  G0 triangle + s0
    float* w = acc + 48;             // [48..55] w coefficients

    hipMemsetAsync(d_ws, 0, 44 * sizeof(float), stream);

    gemm_xxt<<<dim3(32, 32), 256, 0, stream>>>(X, Y);
    gram_kernel<<<256, 256, 0, stream>>>(A, Y, acc);
    iterate_kernel<<<1, 64, 0, stream>>>(acc, Kp, w);
    reconstruct<<<2048, 256, 0, stream>>>(A, w, Y);
}

// Round 3
// 101.092 us; speedup vs baseline: 2.1606x; 1.4210x over previous
//
#include <hip/hip_runtime.h>

#define NN 2048
#define DD 512
#define MM 8

typedef __attribute__((ext_vector_type(8))) short short8_t;   // 8 x bf16 bits (4 VGPR)
typedef __attribute__((ext_vector_type(4))) float f32x4_t;    // MFMA 16x16 accumulator

#define AS1 __attribute__((address_space(1)))
#define AS3 __attribute__((address_space(3)))

__host__ __device__ constexpr int tri_idx(int m, int mm) {
    return m * 8 - m * (m + 1) / 2 + mm;   // upper-tri packed index, 8x8 -> 36
}

__device__ inline unsigned short f2bf_rne(float f) {
    unsigned int u = __float_as_uint(f);
    u += 0x7FFFu + ((u >> 16) & 1u);       // round-to-nearest-even
    return (unsigned short)(u >> 16);
}
__device__ inline float bf2f(unsigned short h) {
    return __uint_as_float(((unsigned int)h) << 16);
}

// ---------------------------------------------------------------------------
// Kernel 0: split X (fp32 [NN][DD]) into Xhi + Xlo (bf16 bit patterns).
// Block 0 also zeroes the 44 gram accumulators (replaces hipMemsetAsync).
// ---------------------------------------------------------------------------
__global__ __launch_bounds__(256) void convert_split(const float* __restrict__ X,
                                                     unsigned short* __restrict__ Xhi,
                                                     unsigned short* __restrict__ Xlo,
                                                     float* __restrict__ acc) {
    if (blockIdx.x == 0 && threadIdx.x < 44) acc[threadIdx.x] = 0.f;
    const int idx = (blockIdx.x * 256 + threadIdx.x) * 4;   // 1024 blocks covers NN*DD exactly
    float4 v = *reinterpret_cast<const float4*>(&X[idx]);
    float xs[4] = {v.x, v.y, v.z, v.w};
    ushort4 hi, lo;
    unsigned short* hp = &hi.x;
    unsigned short* lp = &lo.x;
    #pragma unroll
    for (int j = 0; j < 4; ++j) {
        unsigned short h = f2bf_rne(xs[j]);
        hp[j] = h;
        lp[j] = f2bf_rne(xs[j] - bf2f(h));
    }
    *reinterpret_cast<ushort4*>(&Xhi[idx]) = hi;
    *reinterpret_cast<ushort4*>(&Xlo[idx]) = lo;
}

// ---------------------------------------------------------------------------
// Kernel 1: Y = Xhi Xhi^T + Xhi Xlo^T + Xlo Xhi^T  via 16x16x32 bf16 MFMA.
// 128x128 tile, BK=32, 256 threads = 4 waves (2x2 of 64x64), grid 16x16.
// global_load_lds (16B) with pre-swizzled global source; swizzled ds_read.
// Swizzle: 16B-chunk g at row r lives at slot g ^ ((r>>1)&3)  (involution).
// ---------------------------------------------------------------------------
__global__ __launch_bounds__(256) void gemm_mfma(const unsigned short* __restrict__ Xhi,
                                                 const unsigned short* __restrict__ Xlo,
                                                 float* __restrict__ Y) {
    __shared__ unsigned short lds[4 * 128 * 32];     // Ahi | Alo | Bhi | Blo, 8 KB each
    unsigned short* bufs[4] = {lds, lds + 4096, lds + 8192, lds + 12288};

    const int tid = threadIdx.x;
    const int lane = tid & 63;
    const int wave = tid >> 6;
    const int wr = wave >> 1;            // wave row 0..1
    const int wc = wave & 1;             // wave col 0..1
    const int rowBase = blockIdx.y * 128;
    const int colBase = blockIdx.x * 128;

    f32x4_t acc[4][4] = {};

    const int r = lane & 15;             // fragment row within 16
    const int gq = lane >> 4;            // k-chunk 0..3 (8 bf16 each)

    for (int k0 = 0; k0 < DD; k0 += 32) {
        __syncthreads();                 // previous tile's reads complete
        // stage 4 buffers: 2 instructions each (256 threads x 16B = 4KB per instr)
        #pragma unroll
        for (int i = 0; i < 2; ++i) {
            const int gc = i * 256 + tid;          // chunk index 0..511
            const int row = gc >> 2;
            const int g = gc & 3;
            const int gsrc = g ^ ((row >> 1) & 3); // pre-swizzled source chunk
            const unsigned short* gA = &Xhi[(rowBase + row) * DD + k0 + gsrc * 8];
            const unsigned short* gAl = &Xlo[(rowBase + row) * DD + k0 + gsrc * 8];
            const unsigned short* gB = &Xhi[(colBase + row) * DD + k0 + gsrc * 8];
            const unsigned short* gBl = &Xlo[(colBase + row) * DD + k0 + gsrc * 8];
            // wave-uniform LDS base: chunks [i*256 + wave*64 ...]
            const int lbase = (i * 256 + wave * 64) * 8;   // in ushorts
            __builtin_amdgcn_global_load_lds((const AS1 unsigned int*)gA,
                                             (AS3 unsigned int*)(bufs[0] + lbase), 16, 0, 0);
            __builtin_amdgcn_global_load_lds((const AS1 unsigned int*)gAl,
                                             (AS3 unsigned int*)(bufs[1] + lbase), 16, 0, 0);
            __builtin_amdgcn_global_load_lds((const AS1 unsigned int*)gB,
                                             (AS3 unsigned int*)(bufs[2] + lbase), 16, 0, 0);
            __builtin_amdgcn_global_load_lds((const AS1 unsigned int*)gBl,
                                             (AS3 unsigned int*)(bufs[3] + lbase), 16, 0, 0);
        }
        __syncthreads();                 // vmcnt(0) drained by compiler before barrier

        short8_t ah[4], al[4], bh[4], bl[4];
        #pragma unroll
        for (int m = 0; m < 4; ++m) {
            const int row = wr * 64 + m * 16 + r;
            const int off = row * 32 + ((gq ^ ((row >> 1) & 3)) * 8);
            ah[m] = *reinterpret_cast<const short8_t*>(&bufs[0][off]);
            al[m] = *reinterpret_cast<const short8_t*>(&bufs[1][off]);
        }
        #pragma unroll
        for (int n = 0; n < 4; ++n) {
            const int row = wc * 64 + n * 16 + r;
            const int off = row * 32 + ((gq ^ ((row >> 1) & 3)) * 8);
            bh[n] = *reinterpret_cast<const short8_t*>(&bufs[2][off]);
            bl[n] = *reinterpret_cast<const short8_t*>(&bufs[3][off]);
        }
        #pragma unroll
        for (int m = 0; m < 4; ++m) {
            #pragma unroll
            for (int n = 0; n < 4; ++n) {
                acc[m][n] = __builtin_amdgcn_mfma_f32_16x16x32_bf16(ah[m], bh[n], acc[m][n], 0, 0, 0);
                acc[m][n] = __builtin_amdgcn_mfma_f32_16x16x32_bf16(ah[m], bl[n], acc[m][n], 0, 0, 0);
                acc[m][n] = __builtin_amdgcn_mfma_f32_16x16x32_bf16(al[m], bh[n], acc[m][n], 0, 0, 0);
            }
        }
    }

    // C/D layout (m89-verified): col = lane&15, row = (lane>>4)*4 + reg
    #pragma unroll
    for (int m = 0; m < 4; ++m) {
        #pragma unroll
        for (int n = 0; n < 4; ++n) {
            #pragma unroll
            for (int j = 0; j < 4; ++j) {
                const int rr = rowBase + wr * 64 + m * 16 + gq * 4 + j;
                const int cc = colBase + wc * 64 + n * 16 + r;
                Y[rr * NN + cc] = acc[m][n][j];
            }
        }
    }
}

// ---------------------------------------------------------------------------
// Kernel 2: G0 (packed upper triangle, 36) and s0 (8) in one 144MB pass.
// out[0..35] = tri(G0), out[36..43] = s0. Zeroed by convert_split.
// ---------------------------------------------------------------------------
__global__ __launch_bounds__(256) void gram_kernel(const float* __restrict__ A,
                                                   const float* __restrict__ Y,
                                                   float* __restrict__ out) {
    const int P4 = (NN * NN) / 4;
    float vals[44];
    #pragma unroll
    for (int i = 0; i < 44; ++i) vals[i] = 0.f;

    const float4* Y4 = reinterpret_cast<const float4*>(Y);
    const float4* A4 = reinterpret_cast<const float4*>(A);
    const int tid = blockIdx.x * blockDim.x + threadIdx.x;
    const int stride = gridDim.x * blockDim.x;

    for (int p = tid; p < P4; p += stride) {
        float4 y = Y4[p];
        float4 a[MM];
        #pragma unroll
        for (int m = 0; m < MM; ++m) a[m] = A4[m * P4 + p];
        #pragma unroll
        for (int m = 0; m < MM; ++m) {
            vals[36 + m] += a[m].x * y.x + a[m].y * y.y + a[m].z * y.z + a[m].w * y.w;
            #pragma unroll
            for (int mm = m; mm < MM; ++mm) {
                vals[tri_idx(m, mm)] += a[m].x * a[mm].x + a[m].y * a[mm].y +
                                        a[m].z * a[mm].z + a[m].w * a[mm].w;
            }
        }
    }

    #pragma unroll
    for (int i = 0; i < 44; ++i) {
        float v = vals[i];
        #pragma unroll
        for (int off = 32; off > 0; off >>= 1) v += __shfl_down(v, off);
        vals[i] = v;
    }

    __shared__ float wsum[4][44];
    const int lane = threadIdx.x & 63;
    const int wv = threadIdx.x >> 6;
    if (lane == 0) {
        #pragma unroll
        for (int i = 0; i < 44; ++i) wsum[wv][i] = vals[i];
    }
    __syncthreads();
    if (threadIdx.x < 44) {
        float s = wsum[0][threadIdx.x] + wsum[1][threadIdx.x] +
                  wsum[2][threadIdx.x] + wsum[3][threadIdx.x];
        atomicAdd(&out[threadIdx.x], s);
    }
}

// ---------------------------------------------------------------------------
// Kernel 3: K deflation iterations in 9-dim coefficient space (fp64).
// Fully unrolled -> G/T/vectors in VGPRs. Writes w[8] (Y = Y0 + sum w_m A0_m).
// ---------------------------------------------------------------------------
__global__ __launch_bounds__(64, 1) void iterate_kernel(const float* __restrict__ acc,
                                                        const int* __restrict__ Kp,
                                                        float* __restrict__ w_out) {
    double G[MM][MM], s0[MM], T[MM][MM], w[MM];
    #pragma unroll
    for (int m = 0; m < MM; ++m) {
        #pragma unroll
        for (int mm = m; mm < MM; ++mm) {
            double v = (double)acc[tri_idx(m, mm)];
            G[m][mm] = v;
            G[mm][m] = v;
        }
    }
    #pragma unroll
    for (int m = 0; m < MM; ++m) s0[m] = (double)acc[36 + m];
    #pragma unroll
    for (int m = 0; m < MM; ++m) {
        w[m] = 0.0;
        #pragma unroll
        for (int k = 0; k < MM; ++k) T[m][k] = (m == k) ? 1.0 : 0.0;
    }

    const int K = *Kp;
    for (int it = 0; it < K; ++it) {
        double sy[MM];
        #pragma unroll
        for (int k = 0; k < MM; ++k) {
            double a = s0[k];
            #pragma unroll
            for (int j = 0; j < MM; ++j) a += G[k][j] * w[j];
            sy[k] = a;
        }
        double s[MM];
        #pragma unroll
        for (int m = 0; m < MM; ++m) {
            double a = 0.0;
            #pragma unroll
            for (int k = 0; k < MM; ++k) a += T[m][k] * sy[k];
            s[m] = a;
        }
        double c[MM];
        #pragma unroll
        for (int k = 0; k < MM; ++k) {
            double a = 0.0;
            #pragma unroll
            for (int m = 0; m < MM; ++m) a += T[m][k] * s[m];
            c[k] = a;
        }
        double Gc[MM];
        #pragma unroll
        for (int k = 0; k < MM; ++k) {
            double a = 0.0;
            #pragma unroll
            for (int j = 0; j < MM; ++j) a += G[k][j] * c[j];
            Gc[k] = a;
        }
        double den = 0.0, num = 0.0;
        #pragma unroll
        for (int k = 0; k < MM; ++k) den += c[k] * Gc[k];
        #pragma unroll
        for (int m = 0; m < MM; ++m) num += s[m] * s[m];
        const double inv_den = 1.0 / den;
        const double alpha = num * inv_den;
        #pragma unroll
        for (int k = 0; k < MM; ++k) w[k] -= alpha * c[k];
        #pragma unroll
        for (int m = 0; m < MM; ++m) {
            double beta = 0.0;
            #pragma unroll
            for (int k = 0; k < MM; ++k) beta += T[m][k] * Gc[k];
            beta *= inv_den;
            #pragma unroll
            for (int k = 0; k < MM; ++k) T[m][k] -= beta * c[k];
        }
    }
    if (threadIdx.x == 0 && blockIdx.x == 0) {
        #pragma unroll
        for (int k = 0; k < MM; ++k) w_out[k] = (float)w[k];
    }
}

// ---------------------------------------------------------------------------
// Kernel 4: Y += sum_m w_m * A0_m   (in place on d_out)
// ---------------------------------------------------------------------------
__global__ __launch_bounds__(256) void reconstruct(const float* __restrict__ A,
                                                   const float* __restrict__ w,
                                                   float* __restrict__ Y) {
    __shared__ float wsh[MM];
    if (threadIdx.x < MM) wsh[threadIdx.x] = w[threadIdx.x];
    __syncthreads();
    float wl[MM];
    #pragma unroll
    for (int m = 0; m < MM; ++m) wl[m] = wsh[m];

    const int P4 = (NN * NN) / 4;
    float4* Y4 = reinterpret_cast<float4*>(Y);
    const float4* A4 = reinterpret_cast<const float4*>(A);
    const int tid = blockIdx.x * blockDim.x + threadIdx.x;
    const int stride = gridDim.x * blockDim.x;

    for (int p = tid; p < P4; p += stride) {
        float4 y = Y4[p];
        #pragma unroll
        for (int m = 0; m < MM; ++m) {
            float4 a = A4[m * P4 + p];
            y.x += wl[m] * a.x;
            y.y += wl[m] * a.y;
            y.z += wl[m] * a.z;
            y.w += wl[m] * a.w;
        }
        Y4[p] = y;
    }
}

extern "C" void kernel_launch(void* const* d_in, const int* in_sizes, int n_in,
                              void* d_out, int out_size, void* d_ws, size_t ws_size,
                              hipStream_t stream) {
    const float* X = (const float*)d_in[0];
    const float* A = (const float*)d_in[1];
    const int* Kp = (const int*)d_in[2];
    float* Y = (float*)d_out;

    float* acc = (float*)d_ws;                       // [0..43]  G0 triangle + s0
    float* w = acc + 48;                             // [48..55] w coefficients
    unsigned short* Xhi = (unsigned short*)((char*)d_ws + 4096);
    unsigned short* Xlo = Xhi + NN * DD;             // 2 MB each

    convert_split<<<1024, 256, 0, stream>>>(X, Xhi, Xlo, acc);
    gemm_mfma<<<dim3(16, 16), 256, 0, stream>>>(Xhi, Xlo, Y);
    gram_kernel<<<256, 256, 0, stream>>>(A, Y, acc);
    iterate_kernel<<<1, 64, 0, stream>>>(acc, Kp, w);
    reconstruct<<<2048, 256, 0, stream>>>(A, w, Y);
}